// Round 5
// baseline (762.201 us; speedup 1.0000x reference)
//
#include <hip/hip_runtime.h>
#include <hip/hip_bf16.h>
#include <math.h>

#define TB 256

typedef short bf16x8 __attribute__((ext_vector_type(8)));
typedef float f32x4 __attribute__((ext_vector_type(4)));
typedef unsigned short ushort_t;
typedef unsigned short us4 __attribute__((ext_vector_type(4)));
typedef unsigned short us8 __attribute__((ext_vector_type(8)));

constexpr int Bc = 64, Lc = 512, Dc = 256;
constexpr float kScale = 0.0625f;   // 1/sqrt(256)
constexpr float kEps = 1e-8f;

// ---------- bf16 helpers (RNE) ----------
__device__ __forceinline__ ushort_t f2bf(float x) {
    union { float f; unsigned u; } v; v.f = x;
    unsigned r = v.u + 0x7fffu + ((v.u >> 16) & 1u);
    return (ushort_t)(r >> 16);
}
__device__ __forceinline__ float bf2f(ushort_t h) {
    union { float f; unsigned u; } v; v.u = ((unsigned)h) << 16;
    return v.f;
}
__device__ __forceinline__ void split1(float x, ushort_t& h, ushort_t& l) {
    h = f2bf(x);
    l = f2bf(x - bf2f(h));
}

__device__ __forceinline__ float sel5(float t0, float t1, float t2, float t3, float t4, int i) {
    float r = t0;
    r = (i == 1) ? t1 : r;
    r = (i == 2) ? t2 : r;
    r = (i == 3) ? t3 : r;
    r = (i == 4) ? t4 : r;
    return r;
}

// LDS tile: 128 rows x 32 ushorts; unit = 8-ushort (16B) group; XOR-swizzle
// breaks the power-of-2 column stride for the 16-lane fragment reads.
__device__ __forceinline__ int swz(int row, int unit) {
    return row * 32 + ((unit ^ ((row >> 1) & 3)) << 3);
}

// ---------------- codes + per-user table ----------------
__global__ __launch_bounds__(TB) void tab_codes_kernel(
    const int* __restrict__ u, const float* __restrict__ user_tables,
    const int* __restrict__ bs_seq, int* __restrict__ codes, float* __restrict__ tabv)
{
    int gid = blockIdx.x * TB + threadIdx.x;
    const int R = Bc * Lc;
    if (gid < R) {
        const int* r = bs_seq + (size_t)gid * 4;
        int c = 0;
        #pragma unroll
        for (int t = 0; t < 4; ++t) c |= (r[t] != 0) << t;
        codes[gid] = c;
    }
    if (gid < Bc * 5) {
        int b = gid / 5, j = gid % 5;
        tabv[gid] = user_tables[(size_t)u[b] * 5 + j] * kScale;
    }
}

// ---------------- weight transpose + split: [256][256] -> W^T hi/lo planes ----------------
struct PtrSet { const float* src[7]; ushort_t* dstH[7]; ushort_t* dstL[7]; };

__global__ __launch_bounds__(TB) void wtrans_kernel(PtrSet ps)
{
    __shared__ alignas(16) float t[32][33];
    const float* S = ps.src[blockIdx.z];
    ushort_t* DH = ps.dstH[blockIdx.z];
    ushort_t* DL = ps.dstL[blockIdx.z];
    const int r0 = blockIdx.y * 32, c0 = blockIdx.x * 32;
    const int tx = threadIdx.x & 31, ty = threadIdx.x >> 5;   // 8 rows/pass
    #pragma unroll
    for (int i = 0; i < 32; i += 8) t[ty + i][tx] = S[(size_t)(r0 + ty + i) * Dc + c0 + tx];
    __syncthreads();
    #pragma unroll
    for (int i = 0; i < 32; i += 8) {
        float v = t[tx][ty + i];
        ushort_t h, l; split1(v, h, l);
        size_t o = (size_t)(c0 + ty + i) * Dc + r0 + tx;
        DH[o] = h; DL[o] = l;
    }
}

// ---------------- prep: x = a+b -> split planes; LN(x) -> split planes ----------------
__global__ __launch_bounds__(TB) void prep_x_kernel(
    const float* __restrict__ a, const float* __restrict__ b,
    const float* __restrict__ lnw, const float* __restrict__ lnb,
    ushort_t* __restrict__ xh, ushort_t* __restrict__ xl,
    ushort_t* __restrict__ lh, ushort_t* __restrict__ ll)
{
    const int lane = threadIdx.x & 63;
    const int wv = threadIdx.x >> 6;
    const int row = blockIdx.x * 4 + wv;
    const int col = lane * 4;
    size_t base = (size_t)row * Dc + col;
    float4 av = *(const float4*)(a + base);
    float4 bv = *(const float4*)(b + base);
    float x4[4] = {av.x + bv.x, av.y + bv.y, av.z + bv.z, av.w + bv.w};
    float s = x4[0] + x4[1] + x4[2] + x4[3];
    float ss = x4[0]*x4[0] + x4[1]*x4[1] + x4[2]*x4[2] + x4[3]*x4[3];
    #pragma unroll
    for (int off = 32; off; off >>= 1) {
        s += __shfl_xor(s, off);
        ss += __shfl_xor(ss, off);
    }
    const float mu = s * (1.0f / Dc);
    const float var = ss * (1.0f / Dc) - mu * mu;
    const float rs = 1.0f / sqrtf(var + kEps);
    float4 w4 = *(const float4*)(lnw + col);
    float4 b4 = *(const float4*)(lnb + col);
    float wv_[4] = {w4.x, w4.y, w4.z, w4.w};
    float bb_[4] = {b4.x, b4.y, b4.z, b4.w};
    us4 XH, XL, LH, LL4;
    #pragma unroll
    for (int j = 0; j < 4; ++j) {
        ushort_t h, l;
        split1(x4[j], h, l); XH[j] = h; XL[j] = l;
        float ln = (x4[j] - mu) * rs * wv_[j] + bb_[j];
        split1(ln, h, l); LH[j] = h; LL4[j] = l;
    }
    *(us4*)(xh + base) = XH;
    *(us4*)(xl + base) = XL;
    *(us4*)(lh + base) = LH;
    *(us4*)(ll + base) = LL4;
}

// ---------------- split-bf16 MFMA GEMM (pre-split operands) ----------------
// C = A[M,K] @ B^T, B stored [N][ldb] k-minor as hi/lo planes.
// AMODE 0: A from hi/lo planes (lda k-minor).  AMODE 1: A = fp32 array, split in-loop.
// CMODE 0: fp32 rows (ldc). CMODE 1: split hi/lo planes, rows. CMODE 2: split planes transposed.
// CADD (CMODE 0 only): accumulate into existing C (deterministic: prior kernel wrote it).
template<int AMODE, int CMODE, bool BIAS, bool SCL, bool CADD>
__global__ __launch_bounds__(TB) void mfma_gemm(
    const ushort_t* __restrict__ aH, const ushort_t* __restrict__ aL,
    const float* __restrict__ a32,
    const ushort_t* __restrict__ bH, const ushort_t* __restrict__ bL,
    const float* __restrict__ bias,
    float* __restrict__ c32, ushort_t* __restrict__ cH, ushort_t* __restrict__ cL,
    int K, int lda, int ldb, int ldc,
    long sA, long sB, long sC, float scale)
{
    __shared__ alignas(16) ushort_t AsH[4096];
    __shared__ alignas(16) ushort_t AsL[4096];
    __shared__ alignas(16) ushort_t BsH[4096];
    __shared__ alignas(16) ushort_t BsL[4096];

    const int tid = threadIdx.x;
    const int bz = blockIdx.z;
    const int row0 = blockIdx.y * 128, col0 = blockIdx.x * 128;
    const int lane = tid & 63, wid = tid >> 6;
    const int wr = (wid >> 1) * 64, wc = (wid & 1) * 64;
    const int fr = lane & 15, fh = lane >> 4;
    const int su = tid & 3, sm = tid >> 2;          // staging unit / row (0..63)

    const int dA0 = swz(sm, su), dA1 = swz(sm + 64, su);

    // k-invariant per-thread source pointers (linear global layout)
    const ushort_t* aHp = nullptr; const ushort_t* aLp = nullptr;
    const float* a32p = nullptr;
    if constexpr (AMODE == 0) {
        aHp = aH + (size_t)bz * sA + (size_t)(row0 + sm) * lda + su * 8;
        aLp = aL + (size_t)bz * sA + (size_t)(row0 + sm) * lda + su * 8;
    } else {
        a32p = a32 + (size_t)bz * sA + (size_t)(row0 + sm) * lda + su * 8;
    }
    const ushort_t* bHp = bH + (size_t)bz * sB + (size_t)(col0 + sm) * ldb + su * 8;
    const ushort_t* bLp = bL + (size_t)bz * sB + (size_t)(col0 + sm) * ldb + su * 8;
    const size_t aHalf = (size_t)64 * lda;
    const size_t bHalf = (size_t)64 * ldb;

    int ai[4], bi[4];
    #pragma unroll
    for (int f = 0; f < 4; ++f) {
        ai[f] = swz(wr + f * 16 + fr, fh);
        bi[f] = swz(wc + f * 16 + fr, fh);
    }

    f32x4 acc[4][4] = {};

    for (int k0 = 0; k0 < K; k0 += 32) {
        // ---- stage A (128 x 32) ----
        if constexpr (AMODE == 0) {
            *(us8*)&AsH[dA0] = *(const us8*)(aHp + k0);
            *(us8*)&AsH[dA1] = *(const us8*)(aHp + aHalf + k0);
            *(us8*)&AsL[dA0] = *(const us8*)(aLp + k0);
            *(us8*)&AsL[dA1] = *(const us8*)(aLp + aHalf + k0);
        } else {
            #pragma unroll
            for (int half = 0; half < 2; ++half) {
                const size_t o = half * aHalf + k0;
                float v[8];
                *(float4*)&v[0] = *(const float4*)(a32p + o);
                *(float4*)&v[4] = *(const float4*)(a32p + o + 4);
                us8 h8, l8;
                #pragma unroll
                for (int j = 0; j < 8; ++j) {
                    ushort_t h, l; split1(v[j], h, l);
                    h8[j] = h; l8[j] = l;
                }
                const int di = half ? dA1 : dA0;
                *(us8*)&AsH[di] = h8;
                *(us8*)&AsL[di] = l8;
            }
        }
        // ---- stage B (128 x 32) ----
        *(us8*)&BsH[dA0] = *(const us8*)(bHp + k0);
        *(us8*)&BsH[dA1] = *(const us8*)(bHp + bHalf + k0);
        *(us8*)&BsL[dA0] = *(const us8*)(bLp + k0);
        *(us8*)&BsL[dA1] = *(const us8*)(bLp + bHalf + k0);
        __syncthreads();

        bf16x8 aHf[4], aLf[4], bHf[4], bLf[4];
        #pragma unroll
        for (int f = 0; f < 4; ++f) {
            aHf[f] = *(const bf16x8*)&AsH[ai[f]];
            aLf[f] = *(const bf16x8*)&AsL[ai[f]];
            bHf[f] = *(const bf16x8*)&BsH[bi[f]];
            bLf[f] = *(const bf16x8*)&BsL[bi[f]];
        }
        // term-major: dependent MFMAs on the same accumulator are 16 apart
        #pragma unroll
        for (int fj = 0; fj < 4; ++fj)
            #pragma unroll
            for (int fi = 0; fi < 4; ++fi)
                acc[fi][fj] = __builtin_amdgcn_mfma_f32_16x16x32_bf16(aHf[fi], bHf[fj], acc[fi][fj], 0, 0, 0);
        #pragma unroll
        for (int fj = 0; fj < 4; ++fj)
            #pragma unroll
            for (int fi = 0; fi < 4; ++fi)
                acc[fi][fj] = __builtin_amdgcn_mfma_f32_16x16x32_bf16(aHf[fi], bLf[fj], acc[fi][fj], 0, 0, 0);
        #pragma unroll
        for (int fj = 0; fj < 4; ++fj)
            #pragma unroll
            for (int fi = 0; fi < 4; ++fi)
                acc[fi][fj] = __builtin_amdgcn_mfma_f32_16x16x32_bf16(aLf[fi], bHf[fj], acc[fi][fj], 0, 0, 0);
        __syncthreads();
    }

    // ---- epilogue ----
    #pragma unroll
    for (int fj = 0; fj < 4; ++fj) {
        const int c = col0 + wc + fj * 16 + fr;
        const float bv = BIAS ? bias[c] : 0.0f;
        #pragma unroll
        for (int fi = 0; fi < 4; ++fi) {
            f32x4 a = acc[fi][fj];
            float o[4];
            #pragma unroll
            for (int j = 0; j < 4; ++j) o[j] = (SCL ? a[j] * scale : a[j]) + bv;
            const int r0 = row0 + wr + fi * 16 + fh * 4;
            if constexpr (CMODE == 0) {
                float* cp = c32 + (size_t)bz * sC + (size_t)r0 * ldc + c;
                #pragma unroll
                for (int j = 0; j < 4; ++j) {
                    if constexpr (CADD) cp[(size_t)j * ldc] += o[j];
                    else                cp[(size_t)j * ldc]  = o[j];
                }
            } else if constexpr (CMODE == 1) {
                #pragma unroll
                for (int j = 0; j < 4; ++j) {
                    ushort_t h, l; split1(o[j], h, l);
                    const size_t idx = (size_t)(r0 + j) * ldc + c;
                    cH[idx] = h; cL[idx] = l;
                }
            } else {
                us4 h4, l4;
                #pragma unroll
                for (int j = 0; j < 4; ++j) {
                    ushort_t h, l; split1(o[j], h, l);
                    h4[j] = h; l4[j] = l;
                }
                *(us4*)(cH + (size_t)c * ldc + r0) = h4;
                *(us4*)(cL + (size_t)c * ldc + r0) = l4;
            }
        }
    }
}

// ---------------- dual softmax (scores + hamming) -> split P planes ----------------
__global__ __launch_bounds__(TB) void softmax_ham_kernel(
    const float* __restrict__ S, const float* __restrict__ mask,
    const int* __restrict__ codes, const float* __restrict__ tabv,
    ushort_t* __restrict__ Ph, ushort_t* __restrict__ Pl)
{
    const int lane = threadIdx.x & 63;
    const int wv = threadIdx.x >> 6;
    const int row = blockIdx.x * 4 + wv;   // b*L + q
    const int b = row >> 9;
    const float* srow = S + (size_t)row * Lc;
    const float* mrow = mask + (size_t)row * Lc;
    const int* crow = codes + (size_t)b * Lc;
    const int cq = codes[row];
    const float t0 = tabv[b * 5 + 0], t1 = tabv[b * 5 + 1], t2 = tabv[b * 5 + 2],
                t3 = tabv[b * 5 + 3], t4 = tabv[b * 5 + 4];
    float sv[8], hv[8];
    #pragma unroll
    for (int h = 0; h < 2; ++h) {
        int k = h * 256 + lane * 4;
        float4 s4 = *(const float4*)(srow + k);
        float4 m4 = *(const float4*)(mrow + k);
        int4 c4 = *(const int4*)(crow + k);
        sv[h * 4 + 0] = s4.x + m4.x;
        sv[h * 4 + 1] = s4.y + m4.y;
        sv[h * 4 + 2] = s4.z + m4.z;
        sv[h * 4 + 3] = s4.w + m4.w;
        hv[h * 4 + 0] = sel5(t0, t1, t2, t3, t4, __popc(cq ^ c4.x)) + m4.x;
        hv[h * 4 + 1] = sel5(t0, t1, t2, t3, t4, __popc(cq ^ c4.y)) + m4.y;
        hv[h * 4 + 2] = sel5(t0, t1, t2, t3, t4, __popc(cq ^ c4.z)) + m4.z;
        hv[h * 4 + 3] = sel5(t0, t1, t2, t3, t4, __popc(cq ^ c4.w)) + m4.w;
    }
    float m1 = -1e30f, m2 = -1e30f;
    #pragma unroll
    for (int i = 0; i < 8; ++i) { m1 = fmaxf(m1, sv[i]); m2 = fmaxf(m2, hv[i]); }
    #pragma unroll
    for (int off = 32; off; off >>= 1) {
        m1 = fmaxf(m1, __shfl_xor(m1, off));
        m2 = fmaxf(m2, __shfl_xor(m2, off));
    }
    float e1 = 0.f, e2 = 0.f;
    #pragma unroll
    for (int i = 0; i < 8; ++i) {
        sv[i] = expf(sv[i] - m1); e1 += sv[i];
        hv[i] = expf(hv[i] - m2); e2 += hv[i];
    }
    #pragma unroll
    for (int off = 32; off; off >>= 1) {
        e1 += __shfl_xor(e1, off);
        e2 += __shfl_xor(e2, off);
    }
    const float r1 = 1.0f / e1, r2 = 1.0f / e2;
    #pragma unroll
    for (int h = 0; h < 2; ++h) {
        int k = h * 256 + lane * 4;
        us4 h4, l4;
        #pragma unroll
        for (int j = 0; j < 4; ++j) {
            float p = sv[h * 4 + j] * r1 + hv[h * 4 + j] * r2;
            ushort_t hh, ll; split1(p, hh, ll);
            h4[j] = hh; l4[j] = ll;
        }
        *(us4*)(Ph + (size_t)row * Lc + k) = h4;
        *(us4*)(Pl + (size_t)row * Lc + k) = l4;
    }
}

// ---------------- final: out = LN(mha + seq + bs) ----------------
__global__ __launch_bounds__(TB) void final_ln_kernel(
    const float* __restrict__ mha, const float* __restrict__ seq,
    const float* __restrict__ bs, const float* __restrict__ w,
    const float* __restrict__ bb, float* __restrict__ out)
{
    const int lane = threadIdx.x & 63;
    const int wv = threadIdx.x >> 6;
    const int row = blockIdx.x * 4 + wv;
    size_t base = (size_t)row * Dc + lane * 4;
    float4 a = *(const float4*)(mha + base);
    float4 b = *(const float4*)(seq + base);
    float4 c = *(const float4*)(bs + base);
    float4 t = make_float4(a.x + b.x + c.x, a.y + b.y + c.y, a.z + b.z + c.z, a.w + b.w + c.w);
    float s = t.x + t.y + t.z + t.w;
    float ss = t.x * t.x + t.y * t.y + t.z * t.z + t.w * t.w;
    #pragma unroll
    for (int off = 32; off; off >>= 1) {
        s += __shfl_xor(s, off);
        ss += __shfl_xor(ss, off);
    }
    float mu = s * (1.0f / Dc);
    float var = ss * (1.0f / Dc) - mu * mu;
    float rs = 1.0f / sqrtf(var + kEps);
    int col = lane * 4;
    float4 o;
    o.x = (t.x - mu) * rs * w[col + 0] + bb[col + 0];
    o.y = (t.y - mu) * rs * w[col + 1] + bb[col + 1];
    o.z = (t.z - mu) * rs * w[col + 2] + bb[col + 2];
    o.w = (t.w - mu) * rs * w[col + 3] + bb[col + 3];
    *(float4*)(out + base) = o;
}

// ---------------- launch ----------------
// Workspace budget (~195.5 MiB total), with liveness-checked aliasing:
//   region X (64 MiB): [xh|xl|lnh|lnl] == Sb (fp32 RL) == x_mha (fp32 RD)
//     timeline per branch: prep writes x/ln -> QKV consume them -> S-GEMM
//     overwrites region as Sb -> softmax consumes Sb -> (branch 2: prep
//     rewrites) -> final GEMM writes x_mha here (after last softmax).
//   q pair (32 MiB)  -> reused as Ph after S-GEMM consumed q
//   k pair (32 MiB)  -> reused as Pl
//   vT pair (32 MiB)
//   O fp32 (32 MiB)  -> PV-ib writes, PV-pb accumulates (CADD)
//   weight planes ~3.5 MiB + codes/tabv
extern "C" void kernel_launch(void* const* d_in, const int* in_sizes, int n_in,
                              void* d_out, int out_size, void* d_ws, size_t ws_size,
                              hipStream_t stream) {
    const int* u            = (const int*)d_in[0];
    const float* seq_logits = (const float*)d_in[1];
    const float* item_emb   = (const float*)d_in[2];
    const float* pos_emb    = (const float*)d_in[3];
    const int* bs_seq       = (const int*)d_in[4];
    const float* bs_emb     = (const float*)d_in[5];
    const float* attn_mask  = (const float*)d_in[6];
    const float* user_tab   = (const float*)d_in[7];
    const float* Wq_ib = (const float*)d_in[8];
    const float* bq_ib = (const float*)d_in[9];
    const float* Wk_ib = (const float*)d_in[10];
    const float* bk_ib = (const float*)d_in[11];
    const float* Wv_ib = (const float*)d_in[12];
    const float* bv_ib = (const float*)d_in[13];
    const float* Wq_pb = (const float*)d_in[14];
    const float* bq_pb = (const float*)d_in[15];
    const float* Wk_pb = (const float*)d_in[16];
    const float* bk_pb = (const float*)d_in[17];
    const float* Wv_pb = (const float*)d_in[18];
    const float* bv_pb = (const float*)d_in[19];
    const float* Wf    = (const float*)d_in[20];
    const float* bf    = (const float*)d_in[21];
    const float* ln_qib_w = (const float*)d_in[22];
    const float* ln_qib_b = (const float*)d_in[23];
    const float* ln_qpb_w = (const float*)d_in[24];
    const float* ln_qpb_b = (const float*)d_in[25];
    const float* ln_f_w   = (const float*)d_in[26];
    const float* ln_f_b   = (const float*)d_in[27];
    float* out = (float*)d_out;

    const size_t RD = (size_t)Bc * Lc * Dc;   // 8388608
    const size_t RL = (size_t)Bc * Lc * Lc;   // 16777216
    const size_t R  = (size_t)Bc * Lc;        // 32768
    const size_t WSZ = (size_t)Dc * Dc;       // 65536

    char* p = (char*)d_ws;
    // region X (64 MiB)
    ushort_t* xh   = (ushort_t*)p;
    ushort_t* xl   = xh + RD;
    ushort_t* lnh  = xl + RD;
    ushort_t* lnl  = lnh + RD;
    float*    Sb   = (float*)p;      // RL floats, same 64 MiB
    float*    x_mha= (float*)p;      // RD floats
    p += RL * 4;
    ushort_t* qh = (ushort_t*)p; ushort_t* ql = qh + RD; p += RD * 4;
    ushort_t* kh = (ushort_t*)p; ushort_t* kl = kh + RD; p += RD * 4;
    ushort_t* vTh = (ushort_t*)p; ushort_t* vTl = vTh + RD; p += RD * 4;
    float* O = (float*)p; p += RD * 4;
    ushort_t* WH[7]; ushort_t* WL[7];
    for (int i = 0; i < 7; ++i) {
        WH[i] = (ushort_t*)p; p += WSZ * 2;
        WL[i] = (ushort_t*)p; p += WSZ * 2;
    }
    float* tabv = (float*)p; p += 512 * 4;
    int* codes  = (int*)p;  p += R * 4;
    ushort_t* Ph = qh;   // RL ushorts spanning qh+ql (q dead after S-GEMM)
    ushort_t* Pl = kh;   // RL ushorts spanning kh+kl

    dim3 blk(TB);
    dim3 gRow((unsigned)(R / 4));
    dim3 gQKV(Dc / 128, (unsigned)(R / 128), 1);   // (2, 256)
    dim3 gS(Lc / 128, Lc / 128, Bc);               // (4, 4, 64)
    dim3 gPV(Dc / 128, Lc / 128, Bc);              // (2, 4, 64)
    const long LD = (long)Lc * Dc;                 // per-batch q/k/v/o stride
    const long LL = (long)Lc * Lc;                 // per-batch S/P stride

    tab_codes_kernel<<<dim3((unsigned)(R / TB)), blk, 0, stream>>>(u, user_tab, bs_seq, codes, tabv);

    PtrSet ps;
    const float* wsrc[7] = {Wq_ib, Wk_ib, Wv_ib, Wq_pb, Wk_pb, Wv_pb, Wf};
    for (int i = 0; i < 7; ++i) { ps.src[i] = wsrc[i]; ps.dstH[i] = WH[i]; ps.dstL[i] = WL[i]; }
    wtrans_kernel<<<dim3(8, 8, 7), blk, 0, stream>>>(ps);

    for (int br = 0; br < 2; ++br) {
        const float* emb = br == 0 ? item_emb : pos_emb;
        const ushort_t* WqH = WH[br * 3 + 0]; const ushort_t* WqL = WL[br * 3 + 0];
        const ushort_t* WkH = WH[br * 3 + 1]; const ushort_t* WkL = WL[br * 3 + 1];
        const ushort_t* WvH = WH[br * 3 + 2]; const ushort_t* WvL = WL[br * 3 + 2];
        const float* bq = br == 0 ? bq_ib : bq_pb;
        const float* bk = br == 0 ? bk_ib : bk_pb;
        const float* bv = br == 0 ? bv_ib : bv_pb;
        const float* lw = br == 0 ? ln_qib_w : ln_qpb_w;
        const float* lb = br == 0 ? ln_qib_b : ln_qpb_b;

        prep_x_kernel<<<gRow, blk, 0, stream>>>(emb, bs_emb, lw, lb, xh, xl, lnh, lnl);
        // q = LN(x) @ Wq^T + bq -> split planes
        mfma_gemm<0, 1, true, false, false><<<gQKV, blk, 0, stream>>>(
            lnh, lnl, nullptr, WqH, WqL, bq, nullptr, qh, ql,
            Dc, Dc, Dc, Dc, 0, 0, 0, 1.0f);
        // k = x @ Wk + bk -> split planes
        mfma_gemm<0, 1, true, false, false><<<gQKV, blk, 0, stream>>>(
            xh, xl, nullptr, WkH, WkL, bk, nullptr, kh, kl,
            Dc, Dc, Dc, Dc, 0, 0, 0, 1.0f);
        // vT = (x @ Wv + bv)^T -> split planes [256][R]
        mfma_gemm<0, 2, true, false, false><<<gQKV, blk, 0, stream>>>(
            xh, xl, nullptr, WvH, WvL, bv, nullptr, vTh, vTl,
            Dc, Dc, Dc, (int)R, 0, 0, 0, 1.0f);
        // S = q @ k^T * scale (batched) -> fp32 Sb (region X; x/ln dead now)
        mfma_gemm<0, 0, false, true, false><<<gS, blk, 0, stream>>>(
            qh, ql, nullptr, kh, kl, nullptr, Sb, nullptr, nullptr,
            Dc, Dc, Dc, Lc, LD, LD, LL, kScale);
        // dual softmax -> P split planes (alias q/k pairs)
        softmax_ham_kernel<<<gRow, blk, 0, stream>>>(Sb, attn_mask, codes, tabv, Ph, Pl);
        // O (+)= P @ V (batched; B = vT slice, ldb = R, per-batch col offset Lc)
        if (br == 0)
            mfma_gemm<0, 0, false, false, false><<<gPV, blk, 0, stream>>>(
                Ph, Pl, nullptr, vTh, vTl, nullptr, O, nullptr, nullptr,
                Lc, Lc, (int)R, Dc, LL, (long)Lc, LD, 1.0f);
        else
            mfma_gemm<0, 0, false, false, true><<<gPV, blk, 0, stream>>>(
                Ph, Pl, nullptr, vTh, vTl, nullptr, O, nullptr, nullptr,
                Lc, Lc, (int)R, Dc, LL, (long)Lc, LD, 1.0f);
    }

    // mha = O @ Wf + bf  (fp32 A, split in-loop) -> x_mha (region X)
    mfma_gemm<1, 0, true, false, false><<<gQKV, blk, 0, stream>>>(
        nullptr, nullptr, O, WH[6], WL[6], bf, x_mha, nullptr, nullptr,
        Dc, Dc, Dc, Dc, 0, 0, 0, 1.0f);

    // out = LN(mha + seq + bs)
    final_ln_kernel<<<gRow, blk, 0, stream>>>(x_mha, seq_logits, bs_emb, ln_f_w, ln_f_b, out);
}

// Round 7
// 756.017 us; speedup vs baseline: 1.0082x; 1.0082x over previous
//
#include <hip/hip_runtime.h>
#include <hip/hip_bf16.h>
#include <math.h>

#define TB 256

typedef short bf16x8 __attribute__((ext_vector_type(8)));
typedef float f32x4 __attribute__((ext_vector_type(4)));
typedef unsigned short ushort_t;
typedef unsigned short us4 __attribute__((ext_vector_type(4)));
typedef unsigned short us8 __attribute__((ext_vector_type(8)));

constexpr int Bc = 64, Lc = 512, Dc = 256;
constexpr float kScale = 0.0625f;   // 1/sqrt(256)
constexpr float kEps = 1e-8f;

// ---------- bf16 helpers (RNE) ----------
__device__ __forceinline__ ushort_t f2bf(float x) {
    union { float f; unsigned u; } v; v.f = x;
    unsigned r = v.u + 0x7fffu + ((v.u >> 16) & 1u);
    return (ushort_t)(r >> 16);
}
__device__ __forceinline__ float bf2f(ushort_t h) {
    union { float f; unsigned u; } v; v.u = ((unsigned)h) << 16;
    return v.f;
}
__device__ __forceinline__ void split1(float x, ushort_t& h, ushort_t& l) {
    h = f2bf(x);
    l = f2bf(x - bf2f(h));
}

// direct global->LDS, 16B/lane; LDS dest must be wave-uniform (HW adds lane*16).
// Cast form below is the one verified to compile on gfx950 (R4 run).
__device__ __forceinline__ void gl_lds16(const ushort_t* g, ushort_t* l) {
    __builtin_amdgcn_global_load_lds(
        (__attribute__((address_space(1))) void*)(g),
        (__attribute__((address_space(3))) void*)(l), 16, 0, 0);
}

__device__ __forceinline__ float sel5(float t0, float t1, float t2, float t3, float t4, int i) {
    float r = t0;
    r = (i == 1) ? t1 : r;
    r = (i == 2) ? t2 : r;
    r = (i == 3) ? t3 : r;
    r = (i == 4) ? t4 : r;
    return r;
}

// LDS tile: 128 rows x 32 ushorts; physical unit p of row r holds logical
// unit p ^ ((r>>1)&3). gl_lds staging achieves this by pre-swizzling the
// per-lane GLOBAL source unit (involution), LDS dest stays linear (rule #21).
__device__ __forceinline__ int swz(int row, int unit) {
    return row * 32 + ((unit ^ ((row >> 1) & 3)) << 3);
}

// ---------------- codes + per-user table ----------------
__global__ __launch_bounds__(TB) void tab_codes_kernel(
    const int* __restrict__ u, const float* __restrict__ user_tables,
    const int* __restrict__ bs_seq, int* __restrict__ codes, float* __restrict__ tabv)
{
    int gid = blockIdx.x * TB + threadIdx.x;
    const int R = Bc * Lc;
    if (gid < R) {
        const int* r = bs_seq + (size_t)gid * 4;
        int c = 0;
        #pragma unroll
        for (int t = 0; t < 4; ++t) c |= (r[t] != 0) << t;
        codes[gid] = c;
    }
    if (gid < Bc * 5) {
        int b = gid / 5, j = gid % 5;
        tabv[gid] = user_tables[(size_t)u[b] * 5 + j] * kScale;
    }
}

// ---------------- weight transpose + split: [256][256] -> W^T hi/lo planes ----------------
struct PtrSet { const float* src[7]; ushort_t* dstH[7]; ushort_t* dstL[7]; };

__global__ __launch_bounds__(TB) void wtrans_kernel(PtrSet ps)
{
    __shared__ alignas(16) float t[32][33];
    const float* S = ps.src[blockIdx.z];
    ushort_t* DH = ps.dstH[blockIdx.z];
    ushort_t* DL = ps.dstL[blockIdx.z];
    const int r0 = blockIdx.y * 32, c0 = blockIdx.x * 32;
    const int tx = threadIdx.x & 31, ty = threadIdx.x >> 5;   // 8 rows/pass
    #pragma unroll
    for (int i = 0; i < 32; i += 8) t[ty + i][tx] = S[(size_t)(r0 + ty + i) * Dc + c0 + tx];
    __syncthreads();
    #pragma unroll
    for (int i = 0; i < 32; i += 8) {
        float v = t[tx][ty + i];
        ushort_t h, l; split1(v, h, l);
        size_t o = (size_t)(c0 + ty + i) * Dc + r0 + tx;
        DH[o] = h; DL[o] = l;
    }
}

// ---------------- prep: x = a+b -> split planes; LN(x) -> split planes ----------------
__global__ __launch_bounds__(TB) void prep_x_kernel(
    const float* __restrict__ a, const float* __restrict__ b,
    const float* __restrict__ lnw, const float* __restrict__ lnb,
    ushort_t* __restrict__ xh, ushort_t* __restrict__ xl,
    ushort_t* __restrict__ lh, ushort_t* __restrict__ ll)
{
    const int lane = threadIdx.x & 63;
    const int wv = threadIdx.x >> 6;
    const int row = blockIdx.x * 4 + wv;
    const int col = lane * 4;
    size_t base = (size_t)row * Dc + col;
    float4 av = *(const float4*)(a + base);
    float4 bv = *(const float4*)(b + base);
    float x4[4] = {av.x + bv.x, av.y + bv.y, av.z + bv.z, av.w + bv.w};
    float s = x4[0] + x4[1] + x4[2] + x4[3];
    float ss = x4[0]*x4[0] + x4[1]*x4[1] + x4[2]*x4[2] + x4[3]*x4[3];
    #pragma unroll
    for (int off = 32; off; off >>= 1) {
        s += __shfl_xor(s, off);
        ss += __shfl_xor(ss, off);
    }
    const float mu = s * (1.0f / Dc);
    const float var = ss * (1.0f / Dc) - mu * mu;
    const float rs = 1.0f / sqrtf(var + kEps);
    float4 w4 = *(const float4*)(lnw + col);
    float4 b4 = *(const float4*)(lnb + col);
    float wv_[4] = {w4.x, w4.y, w4.z, w4.w};
    float bb_[4] = {b4.x, b4.y, b4.z, b4.w};
    us4 XH, XL, LH, LL4;
    #pragma unroll
    for (int j = 0; j < 4; ++j) {
        ushort_t h, l;
        split1(x4[j], h, l); XH[j] = h; XL[j] = l;
        float ln = (x4[j] - mu) * rs * wv_[j] + bb_[j];
        split1(ln, h, l); LH[j] = h; LL4[j] = l;
    }
    *(us4*)(xh + base) = XH;
    *(us4*)(xl + base) = XL;
    *(us4*)(lh + base) = LH;
    *(us4*)(ll + base) = LL4;
}

// ---------------- split-bf16 MFMA GEMM v2 ----------------
// C = A[M,K] @ B^T, B row-major [N][ldb] k-minor hi/lo planes.
// A: direct global->register fragments (no LDS).
//   AMODE 0: A hi/lo planes. AMODE 1: A fp32, split in registers.
// B: double-buffered LDS via global_load_lds, pre-swizzled source.
// CMODE 0: fp32 rows (+CADD accumulate). CMODE 1: split hi/lo planes.
// BIASN: 0 none, 1 per-col, 2 per-row.  SCL: *scale.
// XSWZ: 1-D grid, XCD batch-grouped: all tiles of a batch on one XCD.
template<int AMODE, int CMODE, int BIASN, bool SCL, bool CADD, bool XSWZ>
__global__ __launch_bounds__(TB) void mfma_gemm(
    const ushort_t* __restrict__ aH, const ushort_t* __restrict__ aL,
    const float* __restrict__ a32,
    const ushort_t* __restrict__ bH, const ushort_t* __restrict__ bL,
    const float* __restrict__ bias,
    float* __restrict__ c32, ushort_t* __restrict__ cH, ushort_t* __restrict__ cL,
    int K, int lda, int ldb, int ldc,
    long sA, long sB, long sC, float scale,
    int nxShift, int gShift)
{
    __shared__ alignas(16) ushort_t BsH[2][4096];
    __shared__ alignas(16) ushort_t BsL[2][4096];

    const int tid = threadIdx.x;
    int bx, by, bz;
    if constexpr (XSWZ) {
        const int i = blockIdx.x;
        const int xcd = i & 7;
        const int slot = i >> 3;
        const int tile = slot & ((1 << gShift) - 1);
        bz = xcd + ((slot >> gShift) << 3);
        bx = tile & ((1 << nxShift) - 1);
        by = tile >> nxShift;
    } else {
        bx = blockIdx.x; by = blockIdx.y; bz = blockIdx.z;
    }
    const int row0 = by * 128, col0 = bx * 128;
    const int lane = tid & 63, wid = tid >> 6;
    const int wr = (wid >> 1) * 64, wc = (wid & 1) * 64;
    const int fr = lane & 15, fh = lane >> 4;

    // ---- B staging geometry (per-lane global src, wave-uniform LDS dest) ----
    const int srow  = 16 * wid + (lane >> 2);             // 0..63
    const int sunit = (lane & 3) ^ ((lane >> 3) & 3);     // pre-swizzled unit
    const ushort_t* bSrcH = bH + (size_t)bz * sB + (size_t)(col0 + srow) * ldb + sunit * 8;
    const ushort_t* bSrcL = bL + (size_t)bz * sB + (size_t)(col0 + srow) * ldb + sunit * 8;
    const size_t bHalf = (size_t)64 * ldb;
    const int ldsC = wid * 512;                            // wave chunk (rows 16w..)

    // ---- B fragment read indices (swizzled) ----
    int bi[4];
    #pragma unroll
    for (int f = 0; f < 4; ++f) bi[f] = swz(wc + f * 16 + fr, fh);

    // ---- A fragment pointers (k-invariant) ----
    const ushort_t* aPH[4]; const ushort_t* aPL[4]; const float* aP32[4];
    #pragma unroll
    for (int f = 0; f < 4; ++f) {
        const int r = row0 + wr + f * 16 + fr;
        if constexpr (AMODE == 0) {
            aPH[f] = aH + (size_t)bz * sA + (size_t)r * lda + fh * 8;
            aPL[f] = aL + (size_t)bz * sA + (size_t)r * lda + fh * 8;
        } else {
            aP32[f] = a32 + (size_t)bz * sA + (size_t)r * lda + fh * 8;
        }
    }

    f32x4 acc[4][4] = {};
    const int NT = K >> 5;

    // prologue: stage tile 0 into buf 0
    {
        gl_lds16(bSrcH,         &BsH[0][ldsC]);
        gl_lds16(bSrcH + bHalf, &BsH[0][2048 + ldsC]);
        gl_lds16(bSrcL,         &BsL[0][ldsC]);
        gl_lds16(bSrcL + bHalf, &BsL[0][2048 + ldsC]);
    }

    for (int t = 0; t < NT; ++t) {
        __syncthreads();   // drains stage(t) (vmcnt 0 before barrier); buf reads of t-1 done
        if (t + 1 < NT) {
            const int nb = (t + 1) & 1;
            const ushort_t* hp = bSrcH + (size_t)(t + 1) * 32;
            const ushort_t* lp = bSrcL + (size_t)(t + 1) * 32;
            gl_lds16(hp,         &BsH[nb][ldsC]);
            gl_lds16(hp + bHalf, &BsH[nb][2048 + ldsC]);
            gl_lds16(lp,         &BsL[nb][ldsC]);
            gl_lds16(lp + bHalf, &BsL[nb][2048 + ldsC]);
        }
        const int k0 = t * 32;
        const int cb = t & 1;

        // A fragments -> registers
        bf16x8 aHf[4], aLf[4];
        if constexpr (AMODE == 0) {
            #pragma unroll
            for (int f = 0; f < 4; ++f) {
                aHf[f] = *(const bf16x8*)(aPH[f] + k0);
                aLf[f] = *(const bf16x8*)(aPL[f] + k0);
            }
        } else {
            #pragma unroll
            for (int f = 0; f < 4; ++f) {
                float v[8];
                *(float4*)&v[0] = *(const float4*)(aP32[f] + k0);
                *(float4*)&v[4] = *(const float4*)(aP32[f] + k0 + 4);
                us8 h8, l8;
                #pragma unroll
                for (int j = 0; j < 8; ++j) {
                    ushort_t h, l; split1(v[j], h, l);
                    h8[j] = h; l8[j] = l;
                }
                aHf[f] = (bf16x8)h8; aLf[f] = (bf16x8)l8;
            }
        }
        // B fragments from LDS
        bf16x8 bHf[4], bLf[4];
        #pragma unroll
        for (int f = 0; f < 4; ++f) {
            bHf[f] = *(const bf16x8*)&BsH[cb][bi[f]];
            bLf[f] = *(const bf16x8*)&BsL[cb][bi[f]];
        }
        // term-major MFMA: dependent writes to same acc are 16 apart
        #pragma unroll
        for (int fj = 0; fj < 4; ++fj)
            #pragma unroll
            for (int fi = 0; fi < 4; ++fi)
                acc[fi][fj] = __builtin_amdgcn_mfma_f32_16x16x32_bf16(aHf[fi], bHf[fj], acc[fi][fj], 0, 0, 0);
        #pragma unroll
        for (int fj = 0; fj < 4; ++fj)
            #pragma unroll
            for (int fi = 0; fi < 4; ++fi)
                acc[fi][fj] = __builtin_amdgcn_mfma_f32_16x16x32_bf16(aHf[fi], bLf[fj], acc[fi][fj], 0, 0, 0);
        #pragma unroll
        for (int fj = 0; fj < 4; ++fj)
            #pragma unroll
            for (int fi = 0; fi < 4; ++fi)
                acc[fi][fj] = __builtin_amdgcn_mfma_f32_16x16x32_bf16(aLf[fi], bHf[fj], acc[fi][fj], 0, 0, 0);
    }

    // ---- epilogue ----
    #pragma unroll
    for (int fj = 0; fj < 4; ++fj) {
        const int c = col0 + wc + fj * 16 + fr;
        const float bcol = (BIASN == 1) ? bias[c] : 0.0f;
        #pragma unroll
        for (int fi = 0; fi < 4; ++fi) {
            f32x4 a = acc[fi][fj];
            const int r0 = row0 + wr + fi * 16 + fh * 4;
            float o[4];
            #pragma unroll
            for (int j = 0; j < 4; ++j) {
                float v = SCL ? a[j] * scale : a[j];
                if constexpr (BIASN == 1) v += bcol;
                if constexpr (BIASN == 2) v += bias[r0 + j];
                o[j] = v;
            }
            if constexpr (CMODE == 0) {
                float* cp = c32 + (size_t)bz * sC + (size_t)r0 * ldc + c;
                #pragma unroll
                for (int j = 0; j < 4; ++j) {
                    if constexpr (CADD) cp[(size_t)j * ldc] += o[j];
                    else                cp[(size_t)j * ldc]  = o[j];
                }
            } else {
                #pragma unroll
                for (int j = 0; j < 4; ++j) {
                    ushort_t h, l; split1(o[j], h, l);
                    const size_t idx = (size_t)(r0 + j) * ldc + c;
                    cH[idx] = h; cL[idx] = l;
                }
            }
        }
    }
}

// ---------------- dual softmax (scores + hamming) -> split P planes ----------------
__global__ __launch_bounds__(TB) void softmax_ham_kernel(
    const float* __restrict__ S, const float* __restrict__ mask,
    const int* __restrict__ codes, const float* __restrict__ tabv,
    ushort_t* __restrict__ Ph, ushort_t* __restrict__ Pl)
{
    const int lane = threadIdx.x & 63;
    const int wv = threadIdx.x >> 6;
    const int row = blockIdx.x * 4 + wv;   // b*L + q
    const int b = row >> 9;
    const float* srow = S + (size_t)row * Lc;
    const float* mrow = mask + (size_t)row * Lc;
    const int* crow = codes + (size_t)b * Lc;
    const int cq = codes[row];
    const float t0 = tabv[b * 5 + 0], t1 = tabv[b * 5 + 1], t2 = tabv[b * 5 + 2],
                t3 = tabv[b * 5 + 3], t4 = tabv[b * 5 + 4];
    float sv[8], hv[8];
    #pragma unroll
    for (int h = 0; h < 2; ++h) {
        int k = h * 256 + lane * 4;
        float4 s4 = *(const float4*)(srow + k);
        float4 m4 = *(const float4*)(mrow + k);
        int4 c4 = *(const int4*)(crow + k);
        sv[h * 4 + 0] = s4.x + m4.x;
        sv[h * 4 + 1] = s4.y + m4.y;
        sv[h * 4 + 2] = s4.z + m4.z;
        sv[h * 4 + 3] = s4.w + m4.w;
        hv[h * 4 + 0] = sel5(t0, t1, t2, t3, t4, __popc(cq ^ c4.x)) + m4.x;
        hv[h * 4 + 1] = sel5(t0, t1, t2, t3, t4, __popc(cq ^ c4.y)) + m4.y;
        hv[h * 4 + 2] = sel5(t0, t1, t2, t3, t4, __popc(cq ^ c4.z)) + m4.z;
        hv[h * 4 + 3] = sel5(t0, t1, t2, t3, t4, __popc(cq ^ c4.w)) + m4.w;
    }
    float m1 = -1e30f, m2 = -1e30f;
    #pragma unroll
    for (int i = 0; i < 8; ++i) { m1 = fmaxf(m1, sv[i]); m2 = fmaxf(m2, hv[i]); }
    #pragma unroll
    for (int off = 32; off; off >>= 1) {
        m1 = fmaxf(m1, __shfl_xor(m1, off));
        m2 = fmaxf(m2, __shfl_xor(m2, off));
    }
    float e1 = 0.f, e2 = 0.f;
    #pragma unroll
    for (int i = 0; i < 8; ++i) {
        sv[i] = expf(sv[i] - m1); e1 += sv[i];
        hv[i] = expf(hv[i] - m2); e2 += hv[i];
    }
    #pragma unroll
    for (int off = 32; off; off >>= 1) {
        e1 += __shfl_xor(e1, off);
        e2 += __shfl_xor(e2, off);
    }
    const float r1 = 1.0f / e1, r2 = 1.0f / e2;
    #pragma unroll
    for (int h = 0; h < 2; ++h) {
        int k = h * 256 + lane * 4;
        us4 h4, l4;
        #pragma unroll
        for (int j = 0; j < 4; ++j) {
            float p = sv[h * 4 + j] * r1 + hv[h * 4 + j] * r2;
            ushort_t hh, ll; split1(p, hh, ll);
            h4[j] = hh; l4[j] = ll;
        }
        *(us4*)(Ph + (size_t)row * Lc + k) = h4;
        *(us4*)(Pl + (size_t)row * Lc + k) = l4;
    }
}

// ---------------- final: out = LN(mha + seq + bs) ----------------
__global__ __launch_bounds__(TB) void final_ln_kernel(
    const float* __restrict__ mha, const float* __restrict__ seq,
    const float* __restrict__ bs, const float* __restrict__ w,
    const float* __restrict__ bb, float* __restrict__ out)
{
    const int lane = threadIdx.x & 63;
    const int wv = threadIdx.x >> 6;
    const int row = blockIdx.x * 4 + wv;
    size_t base = (size_t)row * Dc + lane * 4;
    float4 a = *(const float4*)(mha + base);
    float4 b = *(const float4*)(seq + base);
    float4 c = *(const float4*)(bs + base);
    float4 t = make_float4(a.x + b.x + c.x, a.y + b.y + c.y, a.z + b.z + c.z, a.w + b.w + c.w);
    float s = t.x + t.y + t.z + t.w;
    float ss = t.x * t.x + t.y * t.y + t.z * t.z + t.w * t.w;
    #pragma unroll
    for (int off = 32; off; off >>= 1) {
        s += __shfl_xor(s, off);
        ss += __shfl_xor(ss, off);
    }
    float mu = s * (1.0f / Dc);
    float var = ss * (1.0f / Dc) - mu * mu;
    float rs = 1.0f / sqrtf(var + kEps);
    int col = lane * 4;
    float4 o;
    o.x = (t.x - mu) * rs * w[col + 0] + bb[col + 0];
    o.y = (t.y - mu) * rs * w[col + 1] + bb[col + 1];
    o.z = (t.z - mu) * rs * w[col + 2] + bb[col + 2];
    o.w = (t.w - mu) * rs * w[col + 3] + bb[col + 3];
    *(float4*)(out + base) = o;
}

// ---------------- launch ----------------
// Workspace ~195.5 MiB, liveness-aliased (same proven layout as R5-green):
//   region X (64 MiB): [xh|xl|lnh|lnl] == Sb == x_mha
//   q planes (32) -> Ph after S consumed q; k planes (32) -> Pl
//   vT planes (32); O fp32 (32, CADD on branch 2); weights ~3.5 + codes/tabv
extern "C" void kernel_launch(void* const* d_in, const int* in_sizes, int n_in,
                              void* d_out, int out_size, void* d_ws, size_t ws_size,
                              hipStream_t stream) {
    const int* u            = (const int*)d_in[0];
    const float* seq_logits = (const float*)d_in[1];
    const float* item_emb   = (const float*)d_in[2];
    const float* pos_emb    = (const float*)d_in[3];
    const int* bs_seq       = (const int*)d_in[4];
    const float* bs_emb     = (const float*)d_in[5];
    const float* attn_mask  = (const float*)d_in[6];
    const float* user_tab   = (const float*)d_in[7];
    const float* Wq_ib = (const float*)d_in[8];
    const float* bq_ib = (const float*)d_in[9];
    const float* Wk_ib = (const float*)d_in[10];
    const float* bk_ib = (const float*)d_in[11];
    const float* Wv_ib = (const float*)d_in[12];
    const float* bv_ib = (const float*)d_in[13];
    const float* Wq_pb = (const float*)d_in[14];
    const float* bq_pb = (const float*)d_in[15];
    const float* Wk_pb = (const float*)d_in[16];
    const float* bk_pb = (const float*)d_in[17];
    const float* Wv_pb = (const float*)d_in[18];
    const float* bv_pb = (const float*)d_in[19];
    const float* Wf    = (const float*)d_in[20];
    const float* bf    = (const float*)d_in[21];
    const float* ln_qib_w = (const float*)d_in[22];
    const float* ln_qib_b = (const float*)d_in[23];
    const float* ln_qpb_w = (const float*)d_in[24];
    const float* ln_qpb_b = (const float*)d_in[25];
    const float* ln_f_w   = (const float*)d_in[26];
    const float* ln_f_b   = (const float*)d_in[27];
    float* out = (float*)d_out;

    const size_t RD = (size_t)Bc * Lc * Dc;   // 8388608
    const size_t RL = (size_t)Bc * Lc * Lc;   // 16777216
    const size_t R  = (size_t)Bc * Lc;        // 32768
    const size_t WSZ = (size_t)Dc * Dc;       // 65536

    char* p = (char*)d_ws;
    // region X (64 MiB)
    ushort_t* xh   = (ushort_t*)p;
    ushort_t* xl   = xh + RD;
    ushort_t* lnh  = xl + RD;
    ushort_t* lnl  = lnh + RD;
    float*    Sb   = (float*)p;      // RL floats, same 64 MiB
    float*    x_mha= (float*)p;      // RD floats
    p += RL * 4;
    ushort_t* qh = (ushort_t*)p; ushort_t* ql = qh + RD; p += RD * 4;
    ushort_t* kh = (ushort_t*)p; ushort_t* kl = kh + RD; p += RD * 4;
    ushort_t* vTh = (ushort_t*)p; ushort_t* vTl = vTh + RD; p += RD * 4;
    float* O = (float*)p; p += RD * 4;
    ushort_t* WH[7]; ushort_t* WL[7];
    for (int i = 0; i < 7; ++i) {
        WH[i] = (ushort_t*)p; p += WSZ * 2;
        WL[i] = (ushort_t*)p; p += WSZ * 2;
    }
    float* tabv = (float*)p; p += 512 * 4;
    int* codes  = (int*)p;  p += R * 4;
    ushort_t* Ph = qh;   // RL ushorts spanning qh+ql
    ushort_t* Pl = kh;   // RL ushorts spanning kh+kl

    dim3 blk(TB);
    dim3 gRow((unsigned)(R / 4));
    dim3 gQKV(Dc / 128, (unsigned)(R / 128), 1);   // (2, 256): M=R, N=256
    dim3 gVT((unsigned)(R / 128), Dc / 128, 1);    // (256, 2): M=256, N=R
    dim3 gS1(Bc * 16);                             // S: 1-D XCD-grouped
    dim3 gPV1(Bc * 8);                             // PV: 1-D XCD-grouped
    const long LD = (long)Lc * Dc;                 // per-batch q/k/v/o stride
    const long LL = (long)Lc * Lc;                 // per-batch S/P stride

    tab_codes_kernel<<<dim3((unsigned)(R / TB)), blk, 0, stream>>>(u, user_tab, bs_seq, codes, tabv);

    PtrSet ps;
    const float* wsrc[7] = {Wq_ib, Wk_ib, Wv_ib, Wq_pb, Wk_pb, Wv_pb, Wf};
    for (int i = 0; i < 7; ++i) { ps.src[i] = wsrc[i]; ps.dstH[i] = WH[i]; ps.dstL[i] = WL[i]; }
    wtrans_kernel<<<dim3(8, 8, 7), blk, 0, stream>>>(ps);

    for (int br = 0; br < 2; ++br) {
        const float* emb = br == 0 ? item_emb : pos_emb;
        const ushort_t* WqH = WH[br * 3 + 0]; const ushort_t* WqL = WL[br * 3 + 0];
        const ushort_t* WkH = WH[br * 3 + 1]; const ushort_t* WkL = WL[br * 3 + 1];
        const ushort_t* WvH = WH[br * 3 + 2]; const ushort_t* WvL = WL[br * 3 + 2];
        const float* bq = br == 0 ? bq_ib : bq_pb;
        const float* bk = br == 0 ? bk_ib : bk_pb;
        const float* bv = br == 0 ? bv_ib : bv_pb;
        const float* lw = br == 0 ? ln_qib_w : ln_qpb_w;
        const float* lb = br == 0 ? ln_qib_b : ln_qpb_b;

        prep_x_kernel<<<gRow, blk, 0, stream>>>(emb, bs_emb, lw, lb, xh, xl, lnh, lnl);
        // q = LN(x) @ Wq^T + bq -> split planes
        mfma_gemm<0, 1, 1, false, false, false><<<gQKV, blk, 0, stream>>>(
            lnh, lnl, nullptr, WqH, WqL, bq, nullptr, qh, ql,
            Dc, Dc, Dc, Dc, 0, 0, 0, 1.0f, 0, 0);
        // k = x @ Wk + bk -> split planes
        mfma_gemm<0, 1, 1, false, false, false><<<gQKV, blk, 0, stream>>>(
            xh, xl, nullptr, WkH, WkL, bk, nullptr, kh, kl,
            Dc, Dc, Dc, Dc, 0, 0, 0, 1.0f, 0, 0);
        // vT = WvT @ x^T + bv(row) -> split planes [256][R]  (coalesced stores)
        mfma_gemm<0, 1, 2, false, false, false><<<gVT, blk, 0, stream>>>(
            WvH, WvL, nullptr, xh, xl, bv, nullptr, vTh, vTl,
            Dc, Dc, Dc, (int)R, 0, 0, 0, 1.0f, 0, 0);
        // S = q @ k^T * scale (batched, XCD-grouped: 16 tiles/batch)
        mfma_gemm<0, 0, 0, true, false, true><<<gS1, blk, 0, stream>>>(
            qh, ql, nullptr, kh, kl, nullptr, Sb, nullptr, nullptr,
            Dc, Dc, Dc, Lc, LD, LD, LL, kScale, 2, 4);
        // dual softmax -> P split planes (alias q/k pairs)
        softmax_ham_kernel<<<gRow, blk, 0, stream>>>(Sb, attn_mask, codes, tabv, Ph, Pl);
        // O (+)= P @ V (batched, XCD-grouped: 8 tiles/batch; B = vT slice)
        if (br == 0)
            mfma_gemm<0, 0, 0, false, false, true><<<gPV1, blk, 0, stream>>>(
                Ph, Pl, nullptr, vTh, vTl, nullptr, O, nullptr, nullptr,
                Lc, Lc, (int)R, Dc, LL, (long)Lc, LD, 1.0f, 1, 3);
        else
            mfma_gemm<0, 0, 0, false, true, true><<<gPV1, blk, 0, stream>>>(
                Ph, Pl, nullptr, vTh, vTl, nullptr, O, nullptr, nullptr,
                Lc, Lc, (int)R, Dc, LL, (long)Lc, LD, 1.0f, 1, 3);
    }

    // mha = O @ Wf + bf  (fp32 A direct-reg, split in registers) -> x_mha
    mfma_gemm<1, 0, 1, false, false, false><<<gQKV, blk, 0, stream>>>(
        nullptr, nullptr, O, WH[6], WL[6], bf, x_mha, nullptr, nullptr,
        Dc, Dc, Dc, Dc, 0, 0, 0, 1.0f, 0, 0);

    // out = LN(mha + seq + bs)
    final_ln_kernel<<<gRow, blk, 0, stream>>>(x_mha, seq_logits, bs_emb, ln_f_w, ln_f_b, out);
}